// Round 21
// baseline (353.576 us; speedup 1.0000x reference)
//
#include <hip/hip_runtime.h>
#include <hip/hip_bf16.h>
#include <stdint.h>
#include <type_traits>

// B=16384, IN=1024, H=1024, K = IN+H = 2048
// Gate order: 0=i, 1=f, 2=o, 3=u
// ws: Apk2 64 MiB @0  — A pre-tiled: [rowTile=64][slice=64(K32)][rg=8][q=2][lane=64]x16B
//     Bpk2 16 MiB @64MiB — W^T pre-tiled: [colTile=16][slice=64][g=4][ch=2][q=2][lane=64]x16B

typedef short bf16x8 __attribute__((ext_vector_type(8)));
typedef unsigned short u16x8 __attribute__((ext_vector_type(8)));
typedef float f32x16 __attribute__((ext_vector_type(16)));

__device__ __forceinline__ unsigned short f2bf(float f) {
    union { float f; uint32_t u; } v; v.f = f;
    uint32_t r = v.u + 0x7FFFu + ((v.u >> 16) & 1u);   // RNE
    return (unsigned short)(r >> 16);
}

__device__ __forceinline__ float fsig(float x) { return 1.0f / (1.0f + __expf(-x)); }
__device__ __forceinline__ float ftanh(float x) { return 2.0f * fsig(2.0f * x) - 1.0f; }

// ---------------- pack A: [input | prev_h] -> tiled bf16 chunks ----------------
__global__ __launch_bounds__(256) void pack_a_kernel(const float* __restrict__ input,
                                                     const float* __restrict__ prev_h,
                                                     unsigned short* __restrict__ Apk2) {
    int u = blockIdx.x * 256 + threadIdx.x;           // 16B-unit index, 4,194,304 total
    int l = u & 63, q = (u >> 6) & 1, rg = (u >> 7) & 7, t = (u >> 10) & 63, rt = u >> 16;
    int row = rt * 256 + rg * 32 + (l & 31);
    int k0 = t * 32 + (q * 2 + (l >> 5)) * 8;
    const float* src = (k0 < 1024) ? (input + (size_t)row * 1024 + k0)
                                   : (prev_h + (size_t)row * 1024 + (k0 - 1024));
    float4 lo = *(const float4*)src;
    float4 hi = *(const float4*)(src + 4);
    u16x8 o;
    o[0] = f2bf(lo.x); o[1] = f2bf(lo.y); o[2] = f2bf(lo.z); o[3] = f2bf(lo.w);
    o[4] = f2bf(hi.x); o[5] = f2bf(hi.y); o[6] = f2bf(hi.z); o[7] = f2bf(hi.w);
    *(u16x8*)(Apk2 + (size_t)u * 8) = o;              // write coalesced
}

// ---------------- pack B: per-gate W^T -> tiled bf16 chunks ----------------
__global__ __launch_bounds__(256) void pack_b_kernel(
        const float* __restrict__ wxi, const float* __restrict__ wxf,
        const float* __restrict__ wxo, const float* __restrict__ wxu,
        const float* __restrict__ whi, const float* __restrict__ whf,
        const float* __restrict__ who, const float* __restrict__ whu,
        unsigned short* __restrict__ Bpk2) {
    int u = blockIdx.x * 256 + threadIdx.x;           // 1,048,576 units
    int l = u & 63, q = (u >> 6) & 1, ch = (u >> 7) & 1, g = (u >> 8) & 3,
        t = (u >> 10) & 63, ct = u >> 16;
    const float* wx = (g == 0) ? wxi : (g == 1) ? wxf : (g == 2) ? wxo : wxu;
    const float* wh = (g == 0) ? whi : (g == 1) ? whf : (g == 2) ? who : whu;
    int j = ct * 64 + ch * 32 + (l & 31);
    int k0 = t * 32 + (q * 2 + (l >> 5)) * 8;
    const float* src = (k0 < 1024) ? (wx + (size_t)k0 * 1024 + j)
                                   : (wh + (size_t)(k0 - 1024) * 1024 + j);
    u16x8 o;
#pragma unroll
    for (int e = 0; e < 8; ++e) o[e] = f2bf(src[(size_t)e * 1024]);
    *(u16x8*)(Bpk2 + (size_t)u * 8) = o;
}

// ---------------- fused GEMM + LSTM epilogue (32x32x16, 1 barrier/K-tile) ----------------
// grid 1024 = 64 rowTiles x 16 colTiles; block 512 = 8 waves; wave (wr=w>>1, wc=w&1).
// Per wave: 64 rows x 32 cols x 4 gates -> acc[2][4] f32x16.
// BK=64 (2 pack-slices), 2 x 64 KiB LDS buffers; fragment-major (0 conflicts);
// pack-tiled linear GLL staging (coalesced). Per K-tile 4 phases (ks=0..3):
//  p0: rd6(ks0); GLL A-chunks j0,j1 (kt+1 -> other buf); 8 MFMA
//  p1: rd6(ks1); GLL A j2,j3;                             8 MFMA
//  p2: rd6(ks2); GLL B j0..j3? -> j0,j1 here, j2,j3 at... (see below)
//  p3: rd6(ks3); vmcnt(0); BAR; 8 MFMA
// Staging spread p0(A2) p1(A2+B2) p2(B2): freshest GLL at the p3 wait has >=1
// phase (~600 cyc) lead > L2 latency (B panels L2-resident). All staging to the
// OTHER buffer -> no in-place WAR -> single barrier (publish) per K-tile.

#define GLL(gp, lp) __builtin_amdgcn_global_load_lds( \
        (__attribute__((address_space(1))) void*)(gp), \
        (__attribute__((address_space(3))) void*)(lp), 16, 0, 0)

#define BAR() do { asm volatile("" ::: "memory"); __builtin_amdgcn_s_barrier(); \
                   asm volatile("" ::: "memory"); } while (0)

__global__ __launch_bounds__(512, 2) void lstm_gemm_kernel(
        const unsigned short* __restrict__ Apk2,
        const unsigned short* __restrict__ Bpk2,
        const float* __restrict__ prev_c,
        const float* __restrict__ bi, const float* __restrict__ bf_,
        const float* __restrict__ bo, const float* __restrict__ bu,
        float* __restrict__ out_h, float* __restrict__ out_c) {
    __shared__ __align__(16) unsigned char smem[131072];
    const int tid = threadIdx.x;
    const int w = tid >> 6, l = tid & 63;
    const int l31 = l & 31, l5 = l >> 5;
    const int wr = w >> 1, wc = w & 1;

    // XCD-aware bijective swizzle (nwg=1024 % 8 == 0)
    const int bid = blockIdx.x;
    const int sw = ((bid & 7) << 7) + (bid >> 3);
    const int tileRow = sw & 63, tileCol = sw >> 6;
    const int rowBase = tileRow * 256;
    const int jBase = tileCol * 64;

    // fragment read offsets (bytes). A region [0,32768): [half][rg8][q2][l]x16B
    // B region [32768,65536): [half][cc16][l]x16B with cc = g*4 + ch*2 + q.
    int aoff[2][4], boff[4][4];
#pragma unroll
    for (int m = 0; m < 2; ++m)
#pragma unroll
        for (int ks = 0; ks < 4; ++ks)
            aoff[m][ks] = (ks >> 1) * 16384 + ((wr * 2 + m) * 2 + (ks & 1)) * 1024 + l * 16;
#pragma unroll
    for (int g = 0; g < 4; ++g)
#pragma unroll
        for (int ks = 0; ks < 4; ++ks)
            boff[g][ks] = 32768 + (ks >> 1) * 16384 + (g * 4 + wc * 2 + (ks & 1)) * 1024 + l * 16;

    // staging: wave w owns chunks c = w*4+j (half=w>>2, cc=(w&3)*4+j); linear src
    const unsigned short* aSrcW = Apk2 + (size_t)tileRow * 524288
                                + (size_t)(w >> 2) * 8192 + ((w & 3) * 4) * 512 + l * 8;
    const unsigned short* bSrcW = Bpk2 + (size_t)tileCol * 524288
                                + (size_t)(w >> 2) * 8192 + ((w & 3) * 4) * 512 + l * 8;
    const int aDstW = w * 4096;            // = (w>>2)*16384 + (w&3)*4096
    const int bDstW = 32768 + w * 4096;

#define STAGE_A1(KT, J) GLL(aSrcW + (size_t)(KT) * 16384 + (J) * 512, \
                            smem + ((((KT) & 1)) * 65536) + aDstW + (J) * 1024)
#define STAGE_B1(KT, J) GLL(bSrcW + (size_t)(KT) * 16384 + (J) * 512, \
                            smem + ((((KT) & 1)) * 65536) + bDstW + (J) * 1024)

    f32x16 acc[2][4];
#pragma unroll
    for (int m = 0; m < 2; ++m)
#pragma unroll
        for (int g = 0; g < 4; ++g)
#pragma unroll
            for (int q = 0; q < 16; ++q) acc[m][g][q] = 0.f;

    // prologue: stage K-tile 0 fully into buf0; drain; publish
    STAGE_A1(0, 0); STAGE_A1(0, 1); STAGE_A1(0, 2); STAGE_A1(0, 3);
    STAGE_B1(0, 0); STAGE_B1(0, 1); STAGE_B1(0, 2); STAGE_B1(0, 3);
    asm volatile("s_waitcnt vmcnt(0)" ::: "memory");
    BAR();

    auto ktile = [&](int kt, auto modeC) {
        constexpr int MODE = decltype(modeC)::value;  // 0 steady; 1 last (kt=31)
        const int bufb = (kt & 1) * 65536;
        bf16x8 av[2], bv[4];
        // ---- p0 (ks0) ----
#pragma unroll
        for (int m = 0; m < 2; ++m) av[m] = *(const bf16x8*)(smem + bufb + aoff[m][0]);
#pragma unroll
        for (int g = 0; g < 4; ++g) bv[g] = *(const bf16x8*)(smem + bufb + boff[g][0]);
        if constexpr (MODE == 0) { STAGE_A1(kt + 1, 0); STAGE_A1(kt + 1, 1); }
#pragma unroll
        for (int m = 0; m < 2; ++m)
#pragma unroll
            for (int g = 0; g < 4; ++g)
                acc[m][g] = __builtin_amdgcn_mfma_f32_32x32x16_bf16(av[m], bv[g], acc[m][g], 0, 0, 0);
        // ---- p1 (ks1) ----
#pragma unroll
        for (int m = 0; m < 2; ++m) av[m] = *(const bf16x8*)(smem + bufb + aoff[m][1]);
#pragma unroll
        for (int g = 0; g < 4; ++g) bv[g] = *(const bf16x8*)(smem + bufb + boff[g][1]);
        if constexpr (MODE == 0) { STAGE_A1(kt + 1, 2); STAGE_A1(kt + 1, 3);
                                   STAGE_B1(kt + 1, 0); STAGE_B1(kt + 1, 1); }
#pragma unroll
        for (int m = 0; m < 2; ++m)
#pragma unroll
            for (int g = 0; g < 4; ++g)
                acc[m][g] = __builtin_amdgcn_mfma_f32_32x32x16_bf16(av[m], bv[g], acc[m][g], 0, 0, 0);
        // ---- p2 (ks2) ----
#pragma unroll
        for (int m = 0; m < 2; ++m) av[m] = *(const bf16x8*)(smem + bufb + aoff[m][2]);
#pragma unroll
        for (int g = 0; g < 4; ++g) bv[g] = *(const bf16x8*)(smem + bufb + boff[g][2]);
        if constexpr (MODE == 0) { STAGE_B1(kt + 1, 2); STAGE_B1(kt + 1, 3); }
#pragma unroll
        for (int m = 0; m < 2; ++m)
#pragma unroll
            for (int g = 0; g < 4; ++g)
                acc[m][g] = __builtin_amdgcn_mfma_f32_32x32x16_bf16(av[m], bv[g], acc[m][g], 0, 0, 0);
        // ---- p3 (ks3): reads, publish kt+1, MFMA ----
#pragma unroll
        for (int m = 0; m < 2; ++m) av[m] = *(const bf16x8*)(smem + bufb + aoff[m][3]);
#pragma unroll
        for (int g = 0; g < 4; ++g) bv[g] = *(const bf16x8*)(smem + bufb + boff[g][3]);
        if constexpr (MODE == 0) {
            asm volatile("s_waitcnt vmcnt(0)" ::: "memory");   // freshest has >=1-phase lead
            BAR();                                             // publish kt+1
        }
#pragma unroll
        for (int m = 0; m < 2; ++m)
#pragma unroll
            for (int g = 0; g < 4; ++g)
                acc[m][g] = __builtin_amdgcn_mfma_f32_32x32x16_bf16(av[m], bv[g], acc[m][g], 0, 0, 0);
    };

    using m0 = std::integral_constant<int, 0>;
    using m1 = std::integral_constant<int, 1>;

#pragma unroll 1
    for (int kt = 0; kt < 31; ++kt) ktile(kt, m0{});
    ktile(31, m1{});

    // ---- epilogue: lane-local; C/D: col=l31, row=(q&3)+8*(q>>2)+4*l5 ----
    const int colIdx = jBase + wc * 32 + l31;
    const float vbi = bi[colIdx], vbf = bf_[colIdx], vbo = bo[colIdx], vbu = bu[colIdx];
    const int rowB = rowBase + wr * 64 + 4 * l5;
#pragma unroll
    for (int m = 0; m < 2; ++m) {
#pragma unroll
        for (int q = 0; q < 16; ++q) {
            const int row = rowB + m * 32 + (q & 3) + 8 * (q >> 2);
            const size_t idx = (size_t)row * 1024 + colIdx;
            float zi = acc[m][0][q] + vbi;
            float zf = acc[m][1][q] + vbf;
            float zo = acc[m][2][q] + vbo;
            float zu = acc[m][3][q] + vbu;
            float iv = fsig(zi), fv = fsig(zf), ov = fsig(zo), uv = ftanh(zu);
            float cv = fv * prev_c[idx] + iv * uv;
            out_c[idx] = cv;
            out_h[idx] = ov * ftanh(cv);
        }
    }
#undef STAGE_A1
#undef STAGE_B1
}

extern "C" void kernel_launch(void* const* d_in, const int* in_sizes, int n_in,
                              void* d_out, int out_size, void* d_ws, size_t ws_size,
                              hipStream_t stream) {
    const float* input  = (const float*)d_in[0];
    const float* prev_h = (const float*)d_in[1];
    const float* prev_c = (const float*)d_in[2];
    const float* wxi = (const float*)d_in[3];
    const float* whi = (const float*)d_in[4];
    const float* wxf = (const float*)d_in[5];
    const float* whf = (const float*)d_in[6];
    const float* wxu = (const float*)d_in[7];
    const float* whu = (const float*)d_in[8];
    const float* wxo = (const float*)d_in[9];
    const float* who = (const float*)d_in[10];
    const float* bi  = (const float*)d_in[11];
    const float* bf_ = (const float*)d_in[12];
    const float* bo  = (const float*)d_in[13];
    const float* bu  = (const float*)d_in[14];

    unsigned short* Apk2 = (unsigned short*)d_ws;                                 // 64 MiB
    unsigned short* Bpk2 = (unsigned short*)((char*)d_ws + (size_t)67108864);     // 16 MiB

    float* out_h = (float*)d_out;
    float* out_c = out_h + (size_t)16384 * 1024;

    pack_a_kernel<<<dim3(16384), dim3(256), 0, stream>>>(input, prev_h, Apk2);
    pack_b_kernel<<<dim3(4096), dim3(256), 0, stream>>>(wxi, wxf, wxo, wxu,
                                                        whi, whf, who, whu, Bpk2);
    lstm_gemm_kernel<<<dim3(1024), dim3(512), 0, stream>>>(Apk2, Bpk2, prev_c,
                                                           bi, bf_, bo, bu, out_h, out_c);
}

// Round 22
// 324.339 us; speedup vs baseline: 1.0901x; 1.0901x over previous
//
#include <hip/hip_runtime.h>
#include <hip/hip_bf16.h>
#include <stdint.h>
#include <type_traits>

// B=16384, IN=1024, H=1024, K = IN+H = 2048
// Gate order: 0=i, 1=f, 2=o, 3=u
// ws: A_bf16 [16384][2048] @ 0 (64 MiB); B_bf16 [4][1024][2048] (j-major = W^T) @ 64 MiB

typedef short bf16x8 __attribute__((ext_vector_type(8)));
typedef unsigned short u16x8 __attribute__((ext_vector_type(8)));
typedef float f32x4 __attribute__((ext_vector_type(4)));

__device__ __forceinline__ unsigned short f2bf(float f) {
    union { float f; uint32_t u; } v; v.f = f;
    uint32_t r = v.u + 0x7FFFu + ((v.u >> 16) & 1u);   // RNE
    return (unsigned short)(r >> 16);
}

__device__ __forceinline__ float fsig(float x) { return 1.0f / (1.0f + __expf(-x)); }
__device__ __forceinline__ float ftanh(float x) { return 2.0f * fsig(2.0f * x) - 1.0f; }

// ---------------- pack A: [input | prev_h] -> bf16 [16384][2048] ----------------
__global__ __launch_bounds__(256) void pack_a_kernel(const float* __restrict__ input,
                                                     const float* __restrict__ prev_h,
                                                     unsigned short* __restrict__ Apk) {
    long idx = (long)blockIdx.x * 256 + threadIdx.x;
    long e0 = idx * 8;
    int b = (int)(e0 >> 11);
    int k = (int)(e0 & 2047);
    const float* src = (k < 1024) ? (input + (size_t)b * 1024 + k)
                                  : (prev_h + (size_t)b * 1024 + (k - 1024));
    float4 lo = *(const float4*)src;
    float4 hi = *(const float4*)(src + 4);
    u16x8 o;
    o[0] = f2bf(lo.x); o[1] = f2bf(lo.y); o[2] = f2bf(lo.z); o[3] = f2bf(lo.w);
    o[4] = f2bf(hi.x); o[5] = f2bf(hi.y); o[6] = f2bf(hi.z); o[7] = f2bf(hi.w);
    *(u16x8*)(Apk + e0) = o;
}

// ---------------- pack B: per-gate W^T (j-major) bf16 [4][1024][2048] ----------------
__global__ __launch_bounds__(256) void pack_b_kernel(
        const float* __restrict__ wxi, const float* __restrict__ wxf,
        const float* __restrict__ wxo, const float* __restrict__ wxu,
        const float* __restrict__ whi, const float* __restrict__ whf,
        const float* __restrict__ who, const float* __restrict__ whu,
        unsigned short* __restrict__ Bpk) {
    int idx = blockIdx.x * 256 + threadIdx.x;
    int g  = idx >> 18;
    int r  = idx & 262143;
    int kc = r >> 10;
    int j  = r & 1023;
    const float* wx = (g == 0) ? wxi : (g == 1) ? wxf : (g == 2) ? wxo : wxu;
    const float* wh = (g == 0) ? whi : (g == 1) ? whf : (g == 2) ? who : whu;
    int k0 = kc * 8;
    const float* src = (k0 < 1024) ? (wx + (size_t)k0 * 1024 + j)
                                   : (wh + (size_t)(k0 - 1024) * 1024 + j);
    u16x8 o;
#pragma unroll
    for (int t = 0; t < 8; ++t) o[t] = f2bf(src[(size_t)t * 1024]);
    *(u16x8*)(Bpk + (((size_t)(g * 1024 + j)) << 11) + k0) = o;
}

// ---------------- fused GEMM + LSTM epilogue (8-phase, 2 barriers/K-tile) ----------------
// CONVERGED BEST (R20): 8-phase BK=64, long-lead T4 staging, 2 barriers/K-tile,
// no setprio (lockstep regime, m190), both-sides XOR swizzle (0 conflicts),
// XCD-bijective block swizzle, fully lane-local LSTM epilogue.
// Load-bearing barriers:
//  BAR@p1 — B-region reads (p0/p1) vs in-place B(kt+2) re-stage at p2/p3 (WAR).
//  BAR@p3 (after vmcnt(4)) — publishes kt+1's staged pieces (RAW).
// Staging: p0/p1 stage A(kt+1)->other buf; p2/p3 stage B(kt+2)->current buf
// (B region free after p1); vmcnt(4)@p3 drains exactly kt+1's pieces (issued
// 2-6 phases prior -> no latency stall), keeps B(kt+2) in flight.

#define GLL(gp, lp) __builtin_amdgcn_global_load_lds( \
        (__attribute__((address_space(1))) void*)(gp), \
        (__attribute__((address_space(3))) void*)(lp), 16, 0, 0)

#define BAR() do { asm volatile("" ::: "memory"); __builtin_amdgcn_s_barrier(); \
                   asm volatile("" ::: "memory"); } while (0)

__global__ __launch_bounds__(512, 2) void lstm_gemm_kernel(
        const unsigned short* __restrict__ Apk,   // [16384][2048]
        const unsigned short* __restrict__ Bpk,   // [4][1024][2048] j-major
        const float* __restrict__ prev_c,
        const float* __restrict__ bi, const float* __restrict__ bf_,
        const float* __restrict__ bo, const float* __restrict__ bu,
        float* __restrict__ out_h, float* __restrict__ out_c) {
    __shared__ __align__(16) unsigned char smem[131072];
    const int tid = threadIdx.x;
    const int w = tid >> 6, l = tid & 63;
    const int lr = l & 15, s4 = l >> 4;
    const int wm = w >> 2, wq = w & 3;

    // XCD-aware bijective swizzle (nwg=1024 % 8 == 0)
    const int bid = blockIdx.x;
    const int sw = ((bid & 7) << 7) + (bid >> 3);
    const int tileRow = sw & 63, tileCol = sw >> 6;
    const int rowBase = tileRow * 256;
    const int jBase = tileCol * 64;

    // read-side: slot byte for ks, XORed with row&7 (= lr&7 for all frags)
    const int h7 = lr & 7;
    const int sig0 = ((s4) ^ h7) * 16;          // ks=0
    const int sig1 = ((4 + s4) ^ h7) * 16;      // ks=1
    const int aRdBase = (wm * 128 + lr) * 128;          // A region @ buf+0
    const int bRdBase = 32768 + (wq * 16 + lr) * 128;   // B region @ buf+32768

    // staging: thread writes piece bytes [tid*16]; source pre-swizzled
    const int rloc = tid >> 3;                  // 0..63 (row within 64-row round)
    const int sigS = ((tid & 7) ^ (rloc & 7)) * 8;   // element offset in row
    const unsigned short* aS00 = Apk + (size_t)(rowBase +   0 +  0 + rloc) * 2048 + sigS;
    const unsigned short* aS01 = Apk + (size_t)(rowBase +   0 + 64 + rloc) * 2048 + sigS;
    const unsigned short* aS10 = Apk + (size_t)(rowBase + 128 +  0 + rloc) * 2048 + sigS;
    const unsigned short* aS11 = Apk + (size_t)(rowBase + 128 + 64 + rloc) * 2048 + sigS;
    auto bsrc = [&](int h, int j) {
        int ec = h * 128 + j * 64 + rloc;
        return Bpk + (((size_t)((ec >> 6) * 1024 + jBase + (ec & 63))) << 11) + sigS;
    };
    const unsigned short* bS00 = bsrc(0, 0);
    const unsigned short* bS01 = bsrc(0, 1);
    const unsigned short* bS10 = bsrc(1, 0);
    const unsigned short* bS11 = bsrc(1, 1);

#define STAGE_P(BUFB, P0, P1, DOFF, KT) do { \
        GLL((P0) + (size_t)(KT) * 64, smem + (BUFB) + (DOFF) + w * 1024); \
        GLL((P1) + (size_t)(KT) * 64, smem + (BUFB) + (DOFF) + 8192 + w * 1024); } while (0)

    f32x4 acc[8][4];
    const f32x4 vzero = {0.f, 0.f, 0.f, 0.f};
#pragma unroll
    for (int m = 0; m < 8; ++m)
#pragma unroll
        for (int g = 0; g < 4; ++g) acc[m][g] = vzero;

    bf16x8 aFe[4], aFo[4], bF0[4], bF1[4];

    auto ldA4 = [&](int bufb, int off, bf16x8 (&dst)[4]) {
#pragma unroll
        for (int m = 0; m < 4; ++m)
            dst[m] = *(const bf16x8*)(smem + bufb + aRdBase + off + m * 2048);
    };
    auto ldB4 = [&](int bufb, int sg, bf16x8 (&dst)[4]) {
#pragma unroll
        for (int g = 0; g < 4; ++g)
            dst[g] = *(const bf16x8*)(smem + bufb + bRdBase + sg + g * 8192);
    };

#define MF16(BASE, AR, BR) do { \
        _Pragma("unroll") \
        for (int m = 0; m < 4; ++m) \
            _Pragma("unroll") \
            for (int g = 0; g < 4; ++g) \
                acc[(BASE) + m][g] = __builtin_amdgcn_mfma_f32_16x16x32_bf16((AR)[m], (BR)[g], acc[(BASE) + m][g], 0, 0, 0); \
        } while (0)

    // prologue: kt0 fully (B1,B0,A0,A1 -> buf0), then B1,B0(kt1) -> buf1;
    // vmcnt(4): drains kt0's 8 (oldest), keeps B(kt1)'s 4 in flight.
    STAGE_P(0, bS10, bS11, 32768 + 16384, 0);
    STAGE_P(0, bS00, bS01, 32768, 0);
    STAGE_P(0, aS00, aS01, 0, 0);
    STAGE_P(0, aS10, aS11, 16384, 0);
    STAGE_P(65536, bS10, bS11, 32768 + 16384, 1);
    STAGE_P(65536, bS00, bS01, 32768, 1);
    asm volatile("s_waitcnt vmcnt(4)" ::: "memory");
    BAR();

    auto ktile = [&](int kt, auto modeC) {
        constexpr int MODE = decltype(modeC)::value;  // 0 steady, 1 kt=30, 2 kt=31
        const int bufb = (kt & 1) * 65536;
        const int othb = bufb ^ 65536;
        // ---- p0: (mh0, ks0); stage A0(kt+1) -> other buf ----
        ldB4(bufb, sig0, bF0);
        ldA4(bufb, sig0, aFe);
        if constexpr (MODE <= 1) STAGE_P(othb, aS00, aS01, 0, kt + 1);
        MF16(0, aFe, bF0);
        // ---- p1: (mh0, ks1); stage A1(kt+1) -> other buf ----
        ldB4(bufb, sig1, bF1);
        ldA4(bufb, sig1, aFo);
        if constexpr (MODE <= 1) STAGE_P(othb, aS10, aS11, 16384, kt + 1);
        BAR();   // WAR: B-region reads (p0/p1) vs in-place B re-stage (p2/p3)
        MF16(0, aFo, bF1);
        // ---- p2: (mh1, ks0); stage B1(kt+2) -> CURRENT buf (B free after p1) ----
        ldA4(bufb, 8192 + sig0, aFe);
        if constexpr (MODE == 0) STAGE_P(bufb, bS10, bS11, 32768 + 16384, kt + 2);
        MF16(4, aFe, bF0);
        // ---- p3: (mh1, ks1); stage B0(kt+2) -> CURRENT buf; counted wait ----
        ldA4(bufb, 8192 + sig1, aFo);
        if constexpr (MODE == 0) STAGE_P(bufb, bS00, bS01, 32768, kt + 2);
        if constexpr (MODE == 0)      asm volatile("s_waitcnt vmcnt(4)" ::: "memory");
        else if constexpr (MODE == 1) asm volatile("s_waitcnt vmcnt(0)" ::: "memory");
        BAR();   // RAW: publish kt+1's staged pieces
        MF16(4, aFo, bF1);
    };

    using m0 = std::integral_constant<int, 0>;
    using m1 = std::integral_constant<int, 1>;
    using m2 = std::integral_constant<int, 2>;

#pragma unroll 1
    for (int kt = 0; kt < 30; ++kt) ktile(kt, m0{});
    ktile(30, m1{});
    ktile(31, m2{});

    // ---- epilogue: fully lane-local; acc[m] rows = (m>>2)*64 + (m&3)*16 ----
    const int colIdx = jBase + wq * 16 + lr;
    const float vbi = bi[colIdx], vbf = bf_[colIdx], vbo = bo[colIdx], vbu = bu[colIdx];
    const int rowB = rowBase + wm * 128 + s4 * 4;
#pragma unroll
    for (int m = 0; m < 8; ++m) {
        const int rOff = (m >> 2) * 64 + (m & 3) * 16;
#pragma unroll
        for (int tt = 0; tt < 4; ++tt) {
            const size_t idx = (size_t)(rowB + rOff + tt) * 1024 + colIdx;
            float zi = acc[m][0][tt] + vbi;
            float zf = acc[m][1][tt] + vbf;
            float zo = acc[m][2][tt] + vbo;
            float zu = acc[m][3][tt] + vbu;
            float iv = fsig(zi), fv = fsig(zf), ov = fsig(zo), uv = ftanh(zu);
            float cv = fv * prev_c[idx] + iv * uv;
            out_c[idx] = cv;
            out_h[idx] = ov * ftanh(cv);
        }
    }
#undef STAGE_P
#undef MF16
}

extern "C" void kernel_launch(void* const* d_in, const int* in_sizes, int n_in,
                              void* d_out, int out_size, void* d_ws, size_t ws_size,
                              hipStream_t stream) {
    const float* input  = (const float*)d_in[0];
    const float* prev_h = (const float*)d_in[1];
    const float* prev_c = (const float*)d_in[2];
    const float* wxi = (const float*)d_in[3];
    const float* whi = (const float*)d_in[4];
    const float* wxf = (const float*)d_in[5];
    const float* whf = (const float*)d_in[6];
    const float* wxu = (const float*)d_in[7];
    const float* whu = (const float*)d_in[8];
    const float* wxo = (const float*)d_in[9];
    const float* who = (const float*)d_in[10];
    const float* bi  = (const float*)d_in[11];
    const float* bf_ = (const float*)d_in[12];
    const float* bo  = (const float*)d_in[13];
    const float* bu  = (const float*)d_in[14];

    unsigned short* Apk = (unsigned short*)d_ws;                                  // 64 MiB
    unsigned short* Bpk = (unsigned short*)((char*)d_ws + (size_t)67108864);      // 16 MiB

    float* out_h = (float*)d_out;
    float* out_c = out_h + (size_t)16384 * 1024;

    pack_a_kernel<<<dim3(16384), dim3(256), 0, stream>>>(input, prev_h, Apk);
    pack_b_kernel<<<dim3(4096), dim3(256), 0, stream>>>(wxi, wxf, wxo, wxu,
                                                        whi, whf, who, whu, Bpk);
    lstm_gemm_kernel<<<dim3(1024), dim3(512), 0, stream>>>(Apk, Bpk, prev_c,
                                                           bi, bf_, bo, bu, out_h, out_c);
}